// Round 1
// baseline (1202.479 us; speedup 1.0000x reference)
//
#include <hip/hip_runtime.h>
#include <hip/hip_bf16.h>
#include <math.h>

#define HEADS 8
#define DIMH 64
#define NPIX 1024
#define BATCH 16
#define CIN 512
#define HIDDEN 512
#define OQKV 1536

// ---------------------------------------------------------------------------
// Kernel 1: Karras forced weight norm for both weight matrices.
// wn row r (<1536): from w_qkv; r>=1536: from w_out. All rows have 512 cols.
// wn = w / ((eps + ||row||/sqrt(512)) * sqrt(512))
// ---------------------------------------------------------------------------
__global__ __launch_bounds__(256) void wnorm_kernel(
    const float* __restrict__ wq, const float* __restrict__ wo,
    float* __restrict__ wn)
{
    int row = blockIdx.x;
    const float* src = (row < OQKV) ? (wq + (size_t)row * CIN)
                                    : (wo + (size_t)(row - OQKV) * CIN);
    int t = threadIdx.x;
    float v0 = src[t];
    float v1 = src[t + 256];
    float ss = v0 * v0 + v1 * v1;
    // wave-64 reduction
    #pragma unroll
    for (int off = 32; off >= 1; off >>= 1) ss += __shfl_xor(ss, off);
    __shared__ float red[4];
    if ((t & 63) == 0) red[t >> 6] = ss;
    __syncthreads();
    float total = red[0] + red[1] + red[2] + red[3];
    const float RSQRT512 = 0.044194173824159216f; // 1/sqrt(512)
    const float SQRT512  = 22.627416997969522f;
    float scale = 1.0f / ((1e-4f + sqrtf(total) * RSQRT512) * SQRT512);
    float* dst = wn + (size_t)row * CIN;
    dst[t] = v0 * scale;
    dst[t + 256] = v1 * scale;
}

// ---------------------------------------------------------------------------
// Kernel 2/4: fp32 tiled GEMM  Y[b][o][p] = sum_c W[o][c] * X[b][c][p]
// 64x64 tile, K-tile 16, 16x16 threads, 4x4 micro-tile.
// FUSE=1: epilogue MPAdd with residual (the original x), write d_out.
// ---------------------------------------------------------------------------
template <int FUSE>
__global__ __launch_bounds__(256) void gemm_kernel(
    const float* __restrict__ W, const float* __restrict__ X,
    const float* __restrict__ resid, float* __restrict__ Y,
    int O, int C, int N)
{
    int b  = blockIdx.z;
    int o0 = blockIdx.y * 64;
    int p0 = blockIdx.x * 64;
    int tid = threadIdx.x;
    int tx = tid & 15;  // p
    int ty = tid >> 4;  // o

    __shared__ __align__(16) float sW[16][68];
    __shared__ __align__(16) float sX[16][64];
    float acc[4][4] = {};

    const float* Xb = X + (size_t)b * C * N;

    for (int k0 = 0; k0 < C; k0 += 16) {
        #pragma unroll
        for (int i = 0; i < 4; i++) {
            int id = i * 256 + tid;
            int k = id & 15, o = id >> 4;
            sW[k][o] = W[(size_t)(o0 + o) * C + k0 + k];
        }
        #pragma unroll
        for (int i = 0; i < 4; i++) {
            int id = i * 256 + tid;
            int pp = id & 63, k = id >> 6;
            sX[k][pp] = Xb[(size_t)(k0 + k) * N + p0 + pp];
        }
        __syncthreads();
        #pragma unroll
        for (int kk = 0; kk < 16; kk++) {
            float4 a  = *(const float4*)&sW[kk][ty * 4];
            float4 bv = *(const float4*)&sX[kk][tx * 4];
            float av[4]  = {a.x, a.y, a.z, a.w};
            float bvv[4] = {bv.x, bv.y, bv.z, bv.w};
            #pragma unroll
            for (int i = 0; i < 4; i++)
                #pragma unroll
                for (int j = 0; j < 4; j++)
                    acc[i][j] += av[i] * bvv[j];
        }
        __syncthreads();
    }

    const float INV_DEN = 1.3130643285972254f; // 1/sqrt(0.7^2+0.3^2)
    #pragma unroll
    for (int i = 0; i < 4; i++) {
        int o = o0 + ty * 4 + i;
        size_t base = ((size_t)b * O + o) * N + p0 + tx * 4;
        #pragma unroll
        for (int j = 0; j < 4; j++) {
            float y = acc[i][j];
            if (FUSE) y = (y * 0.7f + resid[base + j] * 0.3f) * INV_DEN;
            Y[base + j] = y;
        }
    }
}

// ---------------------------------------------------------------------------
// Kernel 3: attention. One thread = one q pixel. Block = 256 q pixels, one
// (b,h). K/V staged raw in LDS with per-row pixel-norm scales; online softmax.
// q normalized to q*8/max(||q||,eps); logit = dot(qn, k_raw) * (1/max(||k||,eps))
// (the /8 sim scale cancels one factor of 8); p *= 8/max(||v||,eps) folds the
// v pixel-norm into the softmax weight.
// ---------------------------------------------------------------------------
__global__ __launch_bounds__(256) void attn_kernel(
    const float* __restrict__ qkv,     // [B][1536][1024]
    const float* __restrict__ mem_kv,  // [2][8][4][64]
    float* __restrict__ out)           // [B][512][1024]
{
    int b = blockIdx.z, h = blockIdx.y;
    int p = blockIdx.x * 256 + threadIdx.x;

    const float* qb = qkv + ((size_t)b * OQKV + h * DIMH) * NPIX;
    const float* kb = qkv + ((size_t)b * OQKV + HIDDEN + h * DIMH) * NPIX;
    const float* vb = qkv + ((size_t)b * OQKV + 2 * HIDDEN + h * DIMH) * NPIX;

    float q[64];
    float ssq = 0.f;
    #pragma unroll
    for (int d = 0; d < 64; d++) {
        q[d] = qb[(size_t)d * NPIX + p];
        ssq += q[d] * q[d];
    }
    float qscale = 8.0f / fmaxf(sqrtf(ssq), 1e-4f);
    #pragma unroll
    for (int d = 0; d < 64; d++) q[d] *= qscale;

    float m = -1e30f, l = 0.f;
    float acc[64];
    #pragma unroll
    for (int d = 0; d < 64; d++) acc[d] = 0.f;

    __shared__ __align__(16) float sK[64][68];
    __shared__ __align__(16) float sV[64][68];
    __shared__ float sKs[64], sVs[64];
    __shared__ float partial[2][4][64];

    // tile -1: 4 mem rows; tiles 0..15: 64 pixel rows each
    for (int tile = -1; tile < 16; ++tile) {
        int rows = (tile < 0) ? 4 : 64;
        __syncthreads();
        int r  = threadIdx.x & 63;
        int dc = (threadIdx.x >> 6) * 16;
        if (r < rows) {
            float ssk = 0.f, ssv = 0.f;
            if (tile < 0) {
                const float* mk = mem_kv + ((size_t)h * 4 + r) * 64;
                const float* mv = mem_kv + ((size_t)(HEADS + h) * 4 + r) * 64;
                #pragma unroll
                for (int i = 0; i < 16; i++) {
                    float kk = mk[dc + i]; sK[r][dc + i] = kk; ssk += kk * kk;
                    float vv = mv[dc + i]; sV[r][dc + i] = vv; ssv += vv * vv;
                }
            } else {
                int pj = tile * 64 + r;
                #pragma unroll
                for (int i = 0; i < 16; i++) {
                    float kk = kb[(size_t)(dc + i) * NPIX + pj]; sK[r][dc + i] = kk; ssk += kk * kk;
                    float vv = vb[(size_t)(dc + i) * NPIX + pj]; sV[r][dc + i] = vv; ssv += vv * vv;
                }
            }
            partial[0][threadIdx.x >> 6][r] = ssk;
            partial[1][threadIdx.x >> 6][r] = ssv;
        }
        __syncthreads();
        if (threadIdx.x < 64 && (int)threadIdx.x < rows) {
            int rr = threadIdx.x;
            float nk = sqrtf(partial[0][0][rr] + partial[0][1][rr] +
                             partial[0][2][rr] + partial[0][3][rr]);
            float nv = sqrtf(partial[1][0][rr] + partial[1][1][rr] +
                             partial[1][2][rr] + partial[1][3][rr]);
            sKs[rr] = 1.0f / fmaxf(nk, 1e-4f);
            sVs[rr] = 8.0f / fmaxf(nv, 1e-4f);
        }
        __syncthreads();

        for (int j = 0; j < rows; j++) {
            float s_ = 0.f;
            #pragma unroll
            for (int d4 = 0; d4 < 64; d4 += 4) {
                float4 k4 = *(const float4*)&sK[j][d4];
                s_ += q[d4] * k4.x + q[d4 + 1] * k4.y + q[d4 + 2] * k4.z + q[d4 + 3] * k4.w;
            }
            s_ *= sKs[j];
            float pw;
            if (s_ <= m) {
                pw = __expf(s_ - m);
                l += pw;
            } else {
                float c = __expf(m - s_);
                l = l * c + 1.0f;
                #pragma unroll
                for (int d = 0; d < 64; d++) acc[d] *= c;
                m = s_;
                pw = 1.0f;
            }
            pw *= sVs[j];
            #pragma unroll
            for (int d4 = 0; d4 < 64; d4 += 4) {
                float4 v4 = *(const float4*)&sV[j][d4];
                acc[d4]     += pw * v4.x;
                acc[d4 + 1] += pw * v4.y;
                acc[d4 + 2] += pw * v4.z;
                acc[d4 + 3] += pw * v4.w;
            }
        }
    }

    float inv_l = 1.0f / l;
    float* ob = out + ((size_t)b * HIDDEN + h * DIMH) * NPIX + p;
    #pragma unroll
    for (int d = 0; d < 64; d++) ob[(size_t)d * NPIX] = acc[d] * inv_l;
}

// ---------------------------------------------------------------------------
extern "C" void kernel_launch(void* const* d_in, const int* in_sizes, int n_in,
                              void* d_out, int out_size, void* d_ws, size_t ws_size,
                              hipStream_t stream)
{
    const float* x      = (const float*)d_in[0];
    const float* w_qkv  = (const float*)d_in[1];
    const float* w_out  = (const float*)d_in[2];
    const float* mem_kv = (const float*)d_in[3];
    float* out = (float*)d_out;

    float* ws   = (float*)d_ws;
    float* wn   = ws;                                   // 2048*512
    float* qkv  = wn + (size_t)2048 * CIN;              // 16*1536*1024
    float* attn = qkv + (size_t)BATCH * OQKV * NPIX;    // 16*512*1024

    wnorm_kernel<<<2048, 256, 0, stream>>>(w_qkv, w_out, wn);

    gemm_kernel<0><<<dim3(NPIX / 64, OQKV / 64, BATCH), 256, 0, stream>>>(
        wn, x, nullptr, qkv, OQKV, CIN, NPIX);

    attn_kernel<<<dim3(NPIX / 256, HEADS, BATCH), 256, 0, stream>>>(
        qkv, mem_kv, attn);

    gemm_kernel<1><<<dim3(NPIX / 64, HIDDEN / 64, BATCH), 256, 0, stream>>>(
        wn + (size_t)OQKV * CIN, attn, x, out, HIDDEN, HIDDEN, NPIX);
}

// Round 2
// 626.559 us; speedup vs baseline: 1.9192x; 1.9192x over previous
//
#include <hip/hip_runtime.h>
#include <hip/hip_bf16.h>
#include <math.h>

#define HEADS 8
#define DIMH 64
#define NPIX 1024
#define BATCH 16
#define CIN 512
#define HIDDEN 512
#define OQKV 1536

typedef __attribute__((ext_vector_type(8))) short v8s;   // 8 x bf16
typedef __attribute__((ext_vector_type(4))) float v4f;
typedef __attribute__((ext_vector_type(4))) int v4i;

#define MFMA16(a, b, c) __builtin_amdgcn_mfma_f32_16x16x32_bf16(a, b, c, 0, 0, 0)

__device__ inline unsigned pkbf(float lo, float hi) {
    unsigned r;
    asm("v_cvt_pk_bf16_f32 %0, %1, %2" : "=v"(r) : "v"(lo), "v"(hi));
    return r;
}

// ---------------------------------------------------------------------------
// Kernel 1: Karras forced weight norm for both weight matrices (fp32).
// ---------------------------------------------------------------------------
__global__ __launch_bounds__(256) void wnorm_kernel(
    const float* __restrict__ wq, const float* __restrict__ wo,
    float* __restrict__ wn)
{
    int row = blockIdx.x;
    const float* src = (row < OQKV) ? (wq + (size_t)row * CIN)
                                    : (wo + (size_t)(row - OQKV) * CIN);
    int t = threadIdx.x;
    float v0 = src[t];
    float v1 = src[t + 256];
    float ss = v0 * v0 + v1 * v1;
    #pragma unroll
    for (int off = 32; off >= 1; off >>= 1) ss += __shfl_xor(ss, off);
    __shared__ float red[4];
    if ((t & 63) == 0) red[t >> 6] = ss;
    __syncthreads();
    float total = red[0] + red[1] + red[2] + red[3];
    const float RSQRT512 = 0.044194173824159216f;
    const float SQRT512  = 22.627416997969522f;
    float scale = 1.0f / ((1e-4f + sqrtf(total) * RSQRT512) * SQRT512);
    float* dst = wn + (size_t)row * CIN;
    dst[t] = v0 * scale;
    dst[t + 256] = v1 * scale;
}

// ---------------------------------------------------------------------------
// Kernel 2: mem_kv prep — bf16 mem K (token-major, padded to 16 rows),
// bf16 mem V (d-major, padded to 32 rows), plus pixel-norm scales.
// ---------------------------------------------------------------------------
__global__ __launch_bounds__(64) void memkv_prep(
    const float* __restrict__ mem_kv,
    __hip_bfloat16* __restrict__ mk, __hip_bfloat16* __restrict__ mv,
    float* __restrict__ msk, float* __restrict__ msv)
{
    int h = blockIdx.x;
    int lane = threadIdx.x;   // 64 = d index
    #pragma unroll
    for (int m = 0; m < 4; m++) {
        float kvv = mem_kv[((size_t)h * 4 + m) * 64 + lane];
        float vvv = mem_kv[((size_t)(HEADS + h) * 4 + m) * 64 + lane];
        float ssk = kvv * kvv, ssv = vvv * vvv;
        #pragma unroll
        for (int off = 32; off >= 1; off >>= 1) {
            ssk += __shfl_xor(ssk, off);
            ssv += __shfl_xor(ssv, off);
        }
        float sck = 8.0f / fmaxf(sqrtf(ssk), 1e-4f);
        float scv = 8.0f / fmaxf(sqrtf(ssv), 1e-4f);
        mk[((size_t)h * 16 + m) * 64 + lane] = __float2bfloat16(kvv);
        mv[((size_t)h * 64 + lane) * 32 + m] = __float2bfloat16(vvv);
        if (lane == 0) { msk[h * 16 + m] = sck; msv[h * 32 + m] = scv; }
    }
    #pragma unroll
    for (int m = 4; m < 16; m++)
        mk[((size_t)h * 16 + m) * 64 + lane] = __float2bfloat16(0.f);
    #pragma unroll
    for (int m = 4; m < 32; m++)
        mv[((size_t)h * 64 + lane) * 32 + m] = __float2bfloat16(0.f);
    if (lane >= 4 && lane < 16) msk[h * 16 + lane] = 0.f;
    if (lane >= 4 && lane < 32) msv[h * 32 + lane] = 0.f;
}

// ---------------------------------------------------------------------------
// Kernel 3: qkv GEMM (fp32 compute) with bf16 + pixel-norm-scale epilogue.
// Q,K written token-major [bh][p][64]; V d-major [bh][64][p].
// Scales: qs = 1/max(||q||,eps); ks = 8/max(||k||,eps); vs = 8/max(||v||,eps).
// ---------------------------------------------------------------------------
__global__ __launch_bounds__(256) void gemm_qkv_kernel(
    const float* __restrict__ W, const float* __restrict__ X,
    __hip_bfloat16* __restrict__ Qb, __hip_bfloat16* __restrict__ Kb,
    __hip_bfloat16* __restrict__ Vb,
    float* __restrict__ qsA, float* __restrict__ ksA, float* __restrict__ vsA)
{
    int b  = blockIdx.z;
    int o0 = blockIdx.y * 64;
    int p0 = blockIdx.x * 64;
    int tid = threadIdx.x;
    int tx = tid & 15, ty = tid >> 4;

    __shared__ __align__(16) float sW[16][68];
    __shared__ __align__(16) float sX[16][64];
    __shared__ float sred[16][65];
    float acc[4][4] = {};
    const float* Xb = X + (size_t)b * CIN * NPIX;

    for (int k0 = 0; k0 < CIN; k0 += 16) {
        #pragma unroll
        for (int i = 0; i < 4; i++) {
            int id = i * 256 + tid;
            int k = id & 15, o = id >> 4;
            sW[k][o] = W[(size_t)(o0 + o) * CIN + k0 + k];
        }
        #pragma unroll
        for (int i = 0; i < 4; i++) {
            int id = i * 256 + tid;
            int pp = id & 63, k = id >> 6;
            sX[k][pp] = Xb[(size_t)(k0 + k) * NPIX + p0 + pp];
        }
        __syncthreads();
        #pragma unroll
        for (int kk = 0; kk < 16; kk++) {
            float4 a  = *(const float4*)&sW[kk][ty * 4];
            float4 bv = *(const float4*)&sX[kk][tx * 4];
            float av[4]  = {a.x, a.y, a.z, a.w};
            float bvv[4] = {bv.x, bv.y, bv.z, bv.w};
            #pragma unroll
            for (int i = 0; i < 4; i++)
                #pragma unroll
                for (int j = 0; j < 4; j++)
                    acc[i][j] += av[i] * bvv[j];
        }
        __syncthreads();
    }

    int part = o0 >> 9;          // 0=q 1=k 2=v
    int h = (o0 >> 6) & 7;
    int bh = b * HEADS + h;

    #pragma unroll
    for (int j = 0; j < 4; j++)
        sred[ty][tx * 4 + j] = acc[0][j] * acc[0][j] + acc[1][j] * acc[1][j]
                             + acc[2][j] * acc[2][j] + acc[3][j] * acc[3][j];
    __syncthreads();
    if (tid < 64) {
        float ss = 0.f;
        #pragma unroll
        for (int yy = 0; yy < 16; yy++) ss += sred[yy][tid];
        float M = fmaxf(sqrtf(ss), 1e-4f);
        float sc = (part == 0) ? (1.0f / M) : (8.0f / M);
        float* dstS = (part == 0) ? qsA : (part == 1) ? ksA : vsA;
        dstS[(size_t)bh * NPIX + p0 + tid] = sc;
    }

    if (part < 2) {
        __hip_bfloat16* dst = ((part == 0) ? Qb : Kb) + (size_t)bh * NPIX * DIMH;
        #pragma unroll
        for (int j = 0; j < 4; j++) {
            int p = p0 + tx * 4 + j;
            union { ushort4 u; __hip_bfloat16 bb[4]; } pk_;
            #pragma unroll
            for (int i = 0; i < 4; i++) pk_.bb[i] = __float2bfloat16(acc[i][j]);
            *reinterpret_cast<ushort4*>(dst + (size_t)p * DIMH + ty * 4) = pk_.u;
        }
    } else {
        __hip_bfloat16* dst = Vb + (size_t)bh * DIMH * NPIX;
        #pragma unroll
        for (int i = 0; i < 4; i++) {
            int d = ty * 4 + i;
            union { ushort4 u; __hip_bfloat16 bb[4]; } pk_;
            #pragma unroll
            for (int j = 0; j < 4; j++) pk_.bb[j] = __float2bfloat16(acc[i][j]);
            *reinterpret_cast<ushort4*>(dst + (size_t)d * NPIX + p0 + tx * 4) = pk_.u;
        }
    }
}

// ---------------------------------------------------------------------------
// Kernel 4: MFMA flash attention. Block=256 (4 waves), wave owns 32 q rows.
// S^T = mfma(Kfrag, Qfrag) -> D[k][q] (k=4*lg+r, q=col). Online softmax with
// cross-lg shfl reduce. P repacked (cvt_pk + 8 shfl) into B-frag layout;
// O^T = mfma(V^T frag, P^T frag) -> D[d][q].
// ---------------------------------------------------------------------------
__global__ __launch_bounds__(256) void attn_mfma_kernel(
    const __hip_bfloat16* __restrict__ Qb,
    const __hip_bfloat16* __restrict__ Kb,
    const __hip_bfloat16* __restrict__ Vb,
    const float* __restrict__ qsA, const float* __restrict__ ksA,
    const float* __restrict__ vsA,
    const __hip_bfloat16* __restrict__ mk, const __hip_bfloat16* __restrict__ mv,
    const float* __restrict__ msk, const float* __restrict__ msv,
    float* __restrict__ out)
{
    int b = blockIdx.z, h = blockIdx.y, bh = b * HEADS + h;
    int wave = threadIdx.x >> 6, lane = threadIdx.x & 63;
    int col = lane & 15, lg = lane >> 4;
    int q0 = blockIdx.x * 128 + wave * 32;

    __shared__ float sKs[NPIX], sVs[NPIX];
    {
        int t4 = threadIdx.x * 4;
        *(float4*)&sKs[t4] = *(const float4*)&ksA[(size_t)bh * NPIX + t4];
        *(float4*)&sVs[t4] = *(const float4*)&vsA[(size_t)bh * NPIX + t4];
    }
    __syncthreads();

    const __hip_bfloat16* Qbase = Qb + ((size_t)bh * NPIX + q0) * DIMH;
    const __hip_bfloat16* Kbase = Kb + (size_t)bh * NPIX * DIMH;
    const __hip_bfloat16* Vbase = Vb + (size_t)bh * DIMH * NPIX;

    v8s qf[2][2];
    float myqs[2];
    #pragma unroll
    for (int qt = 0; qt < 2; qt++) {
        #pragma unroll
        for (int dh = 0; dh < 2; dh++)
            qf[qt][dh] = *(const v8s*)(Qbase + (qt * 16 + col) * DIMH + dh * 32 + 8 * lg);
        myqs[qt] = qsA[(size_t)bh * NPIX + q0 + qt * 16 + col];
    }

    v4f o_[2][4];
    #pragma unroll
    for (int qt = 0; qt < 2; qt++)
        #pragma unroll
        for (int dt = 0; dt < 4; dt++) o_[qt][dt] = (v4f){0.f, 0.f, 0.f, 0.f};
    float m_[2] = {-1e30f, -1e30f};
    float l_[2] = {0.f, 0.f};

    int srcA = ((lg & 1) << 5) + col;
    int srcB = srcA + 16;
    bool hig = (lg >= 2);

    // ---- mem-kv tile: one 16-row k-tile, rows 0..3 valid ----
    {
        const __hip_bfloat16* mkh = mk + (size_t)h * 16 * DIMH;
        v8s kf0 = *(const v8s*)(mkh + col * DIMH + 8 * lg);
        v8s kf1 = *(const v8s*)(mkh + col * DIMH + 32 + 8 * lg);
        v8s vf[4];
        #pragma unroll
        for (int dt = 0; dt < 4; dt++)
            vf[dt] = *(const v8s*)(mv + ((size_t)h * DIMH + dt * 16 + col) * 32 + 8 * lg);
        float4 ksm = *(const float4*)&msk[h * 16 + 4 * lg];
        float4 vsm = *(const float4*)&msv[h * 32 + 4 * lg];
        float ksr[4] = {ksm.x, ksm.y, ksm.z, ksm.w};
        float vsr[4] = {vsm.x, vsm.y, vsm.z, vsm.w};

        #pragma unroll
        for (int qt = 0; qt < 2; qt++) {
            v4f c0 = (v4f){0.f, 0.f, 0.f, 0.f};
            c0 = MFMA16(kf0, qf[qt][0], c0);
            c0 = MFMA16(kf1, qf[qt][1], c0);
            float s0[4], p0[4];
            #pragma unroll
            for (int r = 0; r < 4; r++)
                s0[r] = (lg == 0) ? c0[r] * myqs[qt] * ksr[r] : -1e30f;
            float tm = fmaxf(fmaxf(s0[0], s0[1]), fmaxf(s0[2], s0[3]));
            tm = fmaxf(tm, __shfl_xor(tm, 16));
            tm = fmaxf(tm, __shfl_xor(tm, 32));
            float mnew = fmaxf(m_[qt], tm);
            float fs = __expf(m_[qt] - mnew);
            m_[qt] = mnew;
            float sum = 0.f;
            #pragma unroll
            for (int r = 0; r < 4; r++) { p0[r] = __expf(s0[r] - mnew); sum += p0[r]; }
            sum += __shfl_xor(sum, 16);
            sum += __shfl_xor(sum, 32);
            l_[qt] = l_[qt] * fs + sum;
            #pragma unroll
            for (int dt = 0; dt < 4; dt++) o_[qt][dt] *= fs;

            unsigned A0 = pkbf(p0[0] * vsr[0], p0[1] * vsr[1]);
            unsigned A1 = pkbf(p0[2] * vsr[2], p0[3] * vsr[3]);
            int a0 = __shfl((int)A0, srcA), a1 = __shfl((int)A1, srcA);
            int a2 = __shfl((int)A0, srcB), a3 = __shfl((int)A1, srcB);
            v4i w;
            w.x = hig ? 0 : a0; w.y = hig ? 0 : a1;
            w.z = hig ? 0 : a2; w.w = hig ? 0 : a3;
            v8s pf = __builtin_bit_cast(v8s, w);
            #pragma unroll
            for (int dt = 0; dt < 4; dt++)
                o_[qt][dt] = MFMA16(vf[dt], pf, o_[qt][dt]);
        }
    }

    // ---- main loop: 32 k-rows per tile ----
    for (int k0 = 0; k0 < NPIX; k0 += 32) {
        const __hip_bfloat16* Kr = Kbase + (size_t)k0 * DIMH;
        v8s kf[4];
        kf[0] = *(const v8s*)(Kr + col * DIMH + 8 * lg);
        kf[1] = *(const v8s*)(Kr + col * DIMH + 32 + 8 * lg);
        kf[2] = *(const v8s*)(Kr + (16 + col) * DIMH + 8 * lg);
        kf[3] = *(const v8s*)(Kr + (16 + col) * DIMH + 32 + 8 * lg);
        v8s vf[4];
        #pragma unroll
        for (int dt = 0; dt < 4; dt++)
            vf[dt] = *(const v8s*)(Vbase + (size_t)(dt * 16 + col) * NPIX + k0 + 8 * lg);
        float4 ks0 = *(const float4*)&sKs[k0 + 4 * lg];
        float4 ks1 = *(const float4*)&sKs[k0 + 16 + 4 * lg];
        float4 vs0 = *(const float4*)&sVs[k0 + 4 * lg];
        float4 vs1 = *(const float4*)&sVs[k0 + 16 + 4 * lg];
        float ksr0[4] = {ks0.x, ks0.y, ks0.z, ks0.w};
        float ksr1[4] = {ks1.x, ks1.y, ks1.z, ks1.w};
        float vsr0[4] = {vs0.x, vs0.y, vs0.z, vs0.w};
        float vsr1[4] = {vs1.x, vs1.y, vs1.z, vs1.w};

        #pragma unroll
        for (int qt = 0; qt < 2; qt++) {
            v4f c0 = (v4f){0.f, 0.f, 0.f, 0.f};
            v4f c1 = (v4f){0.f, 0.f, 0.f, 0.f};
            c0 = MFMA16(kf[0], qf[qt][0], c0);
            c0 = MFMA16(kf[1], qf[qt][1], c0);
            c1 = MFMA16(kf[2], qf[qt][0], c1);
            c1 = MFMA16(kf[3], qf[qt][1], c1);

            float s0[4], s1[4], p0[4], p1[4];
            #pragma unroll
            for (int r = 0; r < 4; r++) {
                s0[r] = c0[r] * myqs[qt] * ksr0[r];
                s1[r] = c1[r] * myqs[qt] * ksr1[r];
            }
            float tm = fmaxf(fmaxf(fmaxf(s0[0], s0[1]), fmaxf(s0[2], s0[3])),
                             fmaxf(fmaxf(s1[0], s1[1]), fmaxf(s1[2], s1[3])));
            tm = fmaxf(tm, __shfl_xor(tm, 16));
            tm = fmaxf(tm, __shfl_xor(tm, 32));
            float mnew = fmaxf(m_[qt], tm);
            float fs = __expf(m_[qt] - mnew);
            m_[qt] = mnew;
            float sum = 0.f;
            #pragma unroll
            for (int r = 0; r < 4; r++) {
                p0[r] = __expf(s0[r] - mnew); sum += p0[r];
                p1[r] = __expf(s1[r] - mnew); sum += p1[r];
            }
            sum += __shfl_xor(sum, 16);
            sum += __shfl_xor(sum, 32);
            l_[qt] = l_[qt] * fs + sum;
            #pragma unroll
            for (int dt = 0; dt < 4; dt++) o_[qt][dt] *= fs;

            unsigned A0 = pkbf(p0[0] * vsr0[0], p0[1] * vsr0[1]);
            unsigned A1 = pkbf(p0[2] * vsr0[2], p0[3] * vsr0[3]);
            unsigned B0 = pkbf(p1[0] * vsr1[0], p1[1] * vsr1[1]);
            unsigned B1 = pkbf(p1[2] * vsr1[2], p1[3] * vsr1[3]);
            int a0 = __shfl((int)A0, srcA), a1 = __shfl((int)A1, srcA);
            int a2 = __shfl((int)A0, srcB), a3 = __shfl((int)A1, srcB);
            int b0 = __shfl((int)B0, srcA), b1 = __shfl((int)B1, srcA);
            int b2 = __shfl((int)B0, srcB), b3 = __shfl((int)B1, srcB);
            v4i w;
            w.x = hig ? b0 : a0; w.y = hig ? b1 : a1;
            w.z = hig ? b2 : a2; w.w = hig ? b3 : a3;
            v8s pf = __builtin_bit_cast(v8s, w);
            #pragma unroll
            for (int dt = 0; dt < 4; dt++)
                o_[qt][dt] = MFMA16(vf[dt], pf, o_[qt][dt]);
        }
    }

    // ---- epilogue: O^T[d][q] / l -> out[b][h*64+d][p=q] (fp32 c-major) ----
    #pragma unroll
    for (int qt = 0; qt < 2; qt++) {
        float invl = 1.0f / l_[qt];
        #pragma unroll
        for (int dt = 0; dt < 4; dt++) {
            #pragma unroll
            for (int r = 0; r < 4; r++) {
                out[((size_t)b * HIDDEN + h * DIMH + dt * 16 + 4 * lg + r) * NPIX
                    + q0 + qt * 16 + col] = o_[qt][dt][r] * invl;
            }
        }
    }
}

// ---------------------------------------------------------------------------
// Kernel 5: out-projection GEMM (fp32) with fused MPAdd epilogue.
// ---------------------------------------------------------------------------
template <int FUSE>
__global__ __launch_bounds__(256) void gemm_kernel(
    const float* __restrict__ W, const float* __restrict__ X,
    const float* __restrict__ resid, float* __restrict__ Y,
    int O, int C, int N)
{
    int b  = blockIdx.z;
    int o0 = blockIdx.y * 64;
    int p0 = blockIdx.x * 64;
    int tid = threadIdx.x;
    int tx = tid & 15, ty = tid >> 4;

    __shared__ __align__(16) float sW[16][68];
    __shared__ __align__(16) float sX[16][64];
    float acc[4][4] = {};
    const float* Xb = X + (size_t)b * C * N;

    for (int k0 = 0; k0 < C; k0 += 16) {
        #pragma unroll
        for (int i = 0; i < 4; i++) {
            int id = i * 256 + tid;
            int k = id & 15, o = id >> 4;
            sW[k][o] = W[(size_t)(o0 + o) * C + k0 + k];
        }
        #pragma unroll
        for (int i = 0; i < 4; i++) {
            int id = i * 256 + tid;
            int pp = id & 63, k = id >> 6;
            sX[k][pp] = Xb[(size_t)(k0 + k) * N + p0 + pp];
        }
        __syncthreads();
        #pragma unroll
        for (int kk = 0; kk < 16; kk++) {
            float4 a  = *(const float4*)&sW[kk][ty * 4];
            float4 bv = *(const float4*)&sX[kk][tx * 4];
            float av[4]  = {a.x, a.y, a.z, a.w};
            float bvv[4] = {bv.x, bv.y, bv.z, bv.w};
            #pragma unroll
            for (int i = 0; i < 4; i++)
                #pragma unroll
                for (int j = 0; j < 4; j++)
                    acc[i][j] += av[i] * bvv[j];
        }
        __syncthreads();
    }

    const float INV_DEN = 1.3130643285972254f;
    #pragma unroll
    for (int i = 0; i < 4; i++) {
        int o = o0 + ty * 4 + i;
        size_t base = ((size_t)b * O + o) * N + p0 + tx * 4;
        #pragma unroll
        for (int j = 0; j < 4; j++) {
            float y = acc[i][j];
            if (FUSE) y = (y * 0.7f + resid[base + j] * 0.3f) * INV_DEN;
            Y[base + j] = y;
        }
    }
}

// ---------------------------------------------------------------------------
extern "C" void kernel_launch(void* const* d_in, const int* in_sizes, int n_in,
                              void* d_out, int out_size, void* d_ws, size_t ws_size,
                              hipStream_t stream)
{
    const float* x      = (const float*)d_in[0];
    const float* w_qkv  = (const float*)d_in[1];
    const float* w_out  = (const float*)d_in[2];
    const float* mem_kv = (const float*)d_in[3];
    float* out = (float*)d_out;

    char* ws = (char*)d_ws;
    float* wn  = (float*)ws;  ws += (size_t)2048 * CIN * 4;
    float* att = (float*)ws;  ws += (size_t)BATCH * HIDDEN * NPIX * 4;
    float* qsA = (float*)ws;  ws += (size_t)BATCH * HEADS * NPIX * 4;
    float* ksA = (float*)ws;  ws += (size_t)BATCH * HEADS * NPIX * 4;
    float* vsA = (float*)ws;  ws += (size_t)BATCH * HEADS * NPIX * 4;
    float* msk = (float*)ws;  ws += 8 * 16 * 4;
    float* msv = (float*)ws;  ws += 8 * 32 * 4;
    __hip_bfloat16* Qb = (__hip_bfloat16*)ws; ws += (size_t)BATCH * HEADS * NPIX * DIMH * 2;
    __hip_bfloat16* Kb = (__hip_bfloat16*)ws; ws += (size_t)BATCH * HEADS * NPIX * DIMH * 2;
    __hip_bfloat16* Vb = (__hip_bfloat16*)ws; ws += (size_t)BATCH * HEADS * NPIX * DIMH * 2;
    __hip_bfloat16* mk = (__hip_bfloat16*)ws; ws += (size_t)8 * 16 * 64 * 2;
    __hip_bfloat16* mv = (__hip_bfloat16*)ws; ws += (size_t)8 * 64 * 32 * 2;

    wnorm_kernel<<<2048, 256, 0, stream>>>(w_qkv, w_out, wn);
    memkv_prep<<<8, 64, 0, stream>>>(mem_kv, mk, mv, msk, msv);
    gemm_qkv_kernel<<<dim3(16, 24, BATCH), 256, 0, stream>>>(
        wn, x, Qb, Kb, Vb, qsA, ksA, vsA);
    attn_mfma_kernel<<<dim3(8, HEADS, BATCH), 256, 0, stream>>>(
        Qb, Kb, Vb, qsA, ksA, vsA, mk, mv, msk, msv, att);
    gemm_kernel<1><<<dim3(16, 8, BATCH), 256, 0, stream>>>(
        wn + (size_t)OQKV * CIN, att, x, out, HIDDEN, HIDDEN, NPIX);
}

// Round 3
// 317.327 us; speedup vs baseline: 3.7894x; 1.9745x over previous
//
#include <hip/hip_runtime.h>
#include <hip/hip_bf16.h>
#include <math.h>

#define HEADS 8
#define DIMH 64
#define NPIX 1024
#define BATCH 16
#define CIN 512
#define HIDDEN 512
#define OQKV 1536

typedef __attribute__((ext_vector_type(8))) short v8s;   // 8 x bf16
typedef __attribute__((ext_vector_type(4))) float v4f;
typedef __attribute__((ext_vector_type(4))) int v4i;

#define MFMA16(a, b, c) __builtin_amdgcn_mfma_f32_16x16x32_bf16(a, b, c, 0, 0, 0)

__device__ inline unsigned pkbf(float lo, float hi) {
    unsigned r;
    asm("v_cvt_pk_bf16_f32 %0, %1, %2" : "=v"(r) : "v"(lo), "v"(hi));
    return r;
}
__device__ inline ushort bf16u(float f) {
    __hip_bfloat16 h = __float2bfloat16(f);
    return *(ushort*)&h;
}

// ---------------------------------------------------------------------------
// Kernel 1: Karras weight norm -> bf16 rows. row<1536: w_qkv; else w_out.
// ---------------------------------------------------------------------------
__global__ __launch_bounds__(256) void wnorm_kernel(
    const float* __restrict__ wq, const float* __restrict__ wo,
    ushort* __restrict__ wn)
{
    int row = blockIdx.x;
    const float* src = (row < OQKV) ? (wq + (size_t)row * CIN)
                                    : (wo + (size_t)(row - OQKV) * CIN);
    int t = threadIdx.x;
    float v0 = src[t];
    float v1 = src[t + 256];
    float ss = v0 * v0 + v1 * v1;
    #pragma unroll
    for (int off = 32; off >= 1; off >>= 1) ss += __shfl_xor(ss, off);
    __shared__ float red[4];
    if ((t & 63) == 0) red[t >> 6] = ss;
    __syncthreads();
    float total = red[0] + red[1] + red[2] + red[3];
    const float RSQRT512 = 0.044194173824159216f;
    const float SQRT512  = 22.627416997969522f;
    float scale = 1.0f / ((1e-4f + sqrtf(total) * RSQRT512) * SQRT512);
    ushort* dst = wn + (size_t)row * CIN;
    dst[t] = bf16u(v0 * scale);
    dst[t + 256] = bf16u(v1 * scale);
}

// ---------------------------------------------------------------------------
// Kernel 2: x [b][c][p] f32 -> Xt [b][p][c] bf16 (64x64 LDS tile transpose)
// ---------------------------------------------------------------------------
__global__ __launch_bounds__(256) void xT_kernel(
    const float* __restrict__ x, ushort* __restrict__ Xt)
{
    int b = blockIdx.z;
    int c0 = blockIdx.y * 64;
    int p0 = blockIdx.x * 64;
    __shared__ ushort lds[64][72];
    int tid = threadIdx.x;
    int cl = tid >> 2;
    int pl = (tid & 3) * 16;
    const float* src = x + ((size_t)b * CIN + c0 + cl) * NPIX + p0 + pl;
    #pragma unroll
    for (int j = 0; j < 4; j++) {
        float4 v = *(const float4*)(src + j * 4);
        lds[cl][pl + j * 4 + 0] = bf16u(v.x);
        lds[cl][pl + j * 4 + 1] = bf16u(v.y);
        lds[cl][pl + j * 4 + 2] = bf16u(v.z);
        lds[cl][pl + j * 4 + 3] = bf16u(v.w);
    }
    __syncthreads();
    int pw = tid >> 2;
    int cs = (tid & 3) * 16;
    union { ushort u[16]; uint4 q[2]; } tmp;
    #pragma unroll
    for (int j = 0; j < 16; j++) tmp.u[j] = lds[cs + j][pw];
    ushort* dst = Xt + ((size_t)b * NPIX + p0 + pw) * CIN + c0 + cs;
    *(uint4*)(dst) = tmp.q[0];
    *(uint4*)(dst + 8) = tmp.q[1];
}

// ---------------------------------------------------------------------------
// Kernel 3: mem_kv prep (unchanged from round 2)
// ---------------------------------------------------------------------------
__global__ __launch_bounds__(64) void memkv_prep(
    const float* __restrict__ mem_kv,
    __hip_bfloat16* __restrict__ mk, __hip_bfloat16* __restrict__ mv,
    float* __restrict__ msk, float* __restrict__ msv)
{
    int h = blockIdx.x;
    int lane = threadIdx.x;
    #pragma unroll
    for (int m = 0; m < 4; m++) {
        float kvv = mem_kv[((size_t)h * 4 + m) * 64 + lane];
        float vvv = mem_kv[((size_t)(HEADS + h) * 4 + m) * 64 + lane];
        float ssk = kvv * kvv, ssv = vvv * vvv;
        #pragma unroll
        for (int off = 32; off >= 1; off >>= 1) {
            ssk += __shfl_xor(ssk, off);
            ssv += __shfl_xor(ssv, off);
        }
        float sck = 8.0f / fmaxf(sqrtf(ssk), 1e-4f);
        float scv = 8.0f / fmaxf(sqrtf(ssv), 1e-4f);
        mk[((size_t)h * 16 + m) * 64 + lane] = __float2bfloat16(kvv);
        mv[((size_t)h * 64 + lane) * 32 + m] = __float2bfloat16(vvv);
        if (lane == 0) { msk[h * 16 + m] = sck; msv[h * 32 + m] = scv; }
    }
    #pragma unroll
    for (int m = 4; m < 16; m++)
        mk[((size_t)h * 16 + m) * 64 + lane] = __float2bfloat16(0.f);
    #pragma unroll
    for (int m = 4; m < 32; m++)
        mv[((size_t)h * 64 + lane) * 32 + m] = __float2bfloat16(0.f);
    if (lane >= 4 && lane < 16) msk[h * 16 + lane] = 0.f;
    if (lane >= 4 && lane < 32) msv[h * 32 + lane] = 0.f;
}

// ---------------------------------------------------------------------------
// Kernel 4: Q/K GEMM. MFMA D[o][p] = W·Xt^T. Block 256 = 4 waves (2o x 2p),
// block tile 128x128, wave 64x64, direct global fragment loads, reg dbuf.
// Epilogue: pixel-norm scales (shfl reduce), raw bf16 token-major Q/K.
// ---------------------------------------------------------------------------
__global__ __launch_bounds__(256) void gemm_qk_mfma(
    const ushort* __restrict__ Wb,   // [1024][512]
    const ushort* __restrict__ Xt,   // [B][1024][512]
    ushort* __restrict__ Qb, ushort* __restrict__ Kb,
    float* __restrict__ qsA, float* __restrict__ ksA)
{
    int b = blockIdx.z;
    int o0 = blockIdx.y * 128;
    int p0 = blockIdx.x * 128;
    int wave = threadIdx.x >> 6, lane = threadIdx.x & 63;
    int wy = wave >> 1, wx = wave & 1;
    int col = lane & 15, lg = lane >> 4;
    int ow = o0 + wy * 64, pw = p0 + wx * 64;

    const ushort* Abase = Wb + (size_t)(ow + col) * CIN + 8 * lg;
    const ushort* Bbase = Xt + ((size_t)b * NPIX + pw + col) * CIN + 8 * lg;

    v4f acc[4][4];
    #pragma unroll
    for (int i = 0; i < 4; i++)
        #pragma unroll
        for (int j = 0; j < 4; j++) acc[i][j] = (v4f){0.f, 0.f, 0.f, 0.f};

    v8s a0[4], b0[4], a1[4], b1[4];
    #pragma unroll
    for (int i = 0; i < 4; i++) {
        a0[i] = *(const v8s*)(Abase + (size_t)i * 16 * CIN);
        b0[i] = *(const v8s*)(Bbase + (size_t)i * 16 * CIN);
    }
    #pragma unroll 1
    for (int c0 = 0; c0 < CIN; c0 += 64) {
        #pragma unroll
        for (int i = 0; i < 4; i++) {
            a1[i] = *(const v8s*)(Abase + (size_t)i * 16 * CIN + c0 + 32);
            b1[i] = *(const v8s*)(Bbase + (size_t)i * 16 * CIN + c0 + 32);
        }
        #pragma unroll
        for (int dt = 0; dt < 4; dt++)
            #pragma unroll
            for (int pt = 0; pt < 4; pt++)
                acc[dt][pt] = MFMA16(a0[dt], b0[pt], acc[dt][pt]);
        if (c0 + 64 < CIN) {
            #pragma unroll
            for (int i = 0; i < 4; i++) {
                a0[i] = *(const v8s*)(Abase + (size_t)i * 16 * CIN + c0 + 64);
                b0[i] = *(const v8s*)(Bbase + (size_t)i * 16 * CIN + c0 + 64);
            }
        }
        #pragma unroll
        for (int dt = 0; dt < 4; dt++)
            #pragma unroll
            for (int pt = 0; pt < 4; pt++)
                acc[dt][pt] = MFMA16(a1[dt], b1[pt], acc[dt][pt]);
    }

    int part = ow >> 9;              // 0 = q, 1 = k
    int h = (ow >> 6) & 7;
    int bh = b * HEADS + h;

    float ssq[4];
    #pragma unroll
    for (int pt = 0; pt < 4; pt++) {
        float s = 0.f;
        #pragma unroll
        for (int dt = 0; dt < 4; dt++)
            #pragma unroll
            for (int r = 0; r < 4; r++) s += acc[dt][pt][r] * acc[dt][pt][r];
        s += __shfl_xor(s, 16);
        s += __shfl_xor(s, 32);
        ssq[pt] = s;
    }
    float num = part ? 8.0f : 1.0f;
    if (lg == 0) {
        float* sA = part ? ksA : qsA;
        #pragma unroll
        for (int pt = 0; pt < 4; pt++)
            sA[(size_t)bh * NPIX + pw + pt * 16 + col] =
                num / fmaxf(sqrtf(ssq[pt]), 1e-4f);
    }
    ushort* dst = (part ? Kb : Qb) + (size_t)bh * NPIX * DIMH;
    #pragma unroll
    for (int pt = 0; pt < 4; pt++) {
        int p = pw + pt * 16 + col;
        #pragma unroll
        for (int dt = 0; dt < 4; dt++) {
            uint2 uu;
            uu.x = pkbf(acc[dt][pt][0], acc[dt][pt][1]);
            uu.y = pkbf(acc[dt][pt][2], acc[dt][pt][3]);
            *(uint2*)(dst + (size_t)p * DIMH + dt * 16 + 4 * lg) = uu;
        }
    }
}

// ---------------------------------------------------------------------------
// Kernel 5: V GEMM, swapped orientation: D[p][o] = Xt·Wv^T. Gives contiguous-p
// stores for d-major V. Norm over d = reduce over ot frags + col lanes.
// ---------------------------------------------------------------------------
__global__ __launch_bounds__(256) void gemm_v_mfma(
    const ushort* __restrict__ Wv,   // [512][512] (= wn rows 1024..1536)
    const ushort* __restrict__ Xt,
    ushort* __restrict__ Vb, float* __restrict__ vsA)
{
    int b = blockIdx.z;
    int o0 = blockIdx.y * 128;
    int p0 = blockIdx.x * 128;
    int wave = threadIdx.x >> 6, lane = threadIdx.x & 63;
    int wy = wave >> 1, wx = wave & 1;
    int col = lane & 15, lg = lane >> 4;
    int ow = o0 + wy * 64, pw = p0 + wx * 64;

    const ushort* Abase = Xt + ((size_t)b * NPIX + pw + col) * CIN + 8 * lg;
    const ushort* Bbase = Wv + (size_t)(ow + col) * CIN + 8 * lg;

    v4f acc[4][4];   // [pt][ot]
    #pragma unroll
    for (int i = 0; i < 4; i++)
        #pragma unroll
        for (int j = 0; j < 4; j++) acc[i][j] = (v4f){0.f, 0.f, 0.f, 0.f};

    v8s a0[4], b0[4], a1[4], b1[4];
    #pragma unroll
    for (int i = 0; i < 4; i++) {
        a0[i] = *(const v8s*)(Abase + (size_t)i * 16 * CIN);
        b0[i] = *(const v8s*)(Bbase + (size_t)i * 16 * CIN);
    }
    #pragma unroll 1
    for (int c0 = 0; c0 < CIN; c0 += 64) {
        #pragma unroll
        for (int i = 0; i < 4; i++) {
            a1[i] = *(const v8s*)(Abase + (size_t)i * 16 * CIN + c0 + 32);
            b1[i] = *(const v8s*)(Bbase + (size_t)i * 16 * CIN + c0 + 32);
        }
        #pragma unroll
        for (int pt = 0; pt < 4; pt++)
            #pragma unroll
            for (int ot = 0; ot < 4; ot++)
                acc[pt][ot] = MFMA16(a0[pt], b0[ot], acc[pt][ot]);
        if (c0 + 64 < CIN) {
            #pragma unroll
            for (int i = 0; i < 4; i++) {
                a0[i] = *(const v8s*)(Abase + (size_t)i * 16 * CIN + c0 + 64);
                b0[i] = *(const v8s*)(Bbase + (size_t)i * 16 * CIN + c0 + 64);
            }
        }
        #pragma unroll
        for (int pt = 0; pt < 4; pt++)
            #pragma unroll
            for (int ot = 0; ot < 4; ot++)
                acc[pt][ot] = MFMA16(a1[pt], b1[ot], acc[pt][ot]);
    }

    int h = (ow >> 6) & 7;
    int bh = b * HEADS + h;

    #pragma unroll
    for (int pt = 0; pt < 4; pt++) {
        #pragma unroll
        for (int r = 0; r < 4; r++) {
            float s = acc[pt][0][r] * acc[pt][0][r] + acc[pt][1][r] * acc[pt][1][r]
                    + acc[pt][2][r] * acc[pt][2][r] + acc[pt][3][r] * acc[pt][3][r];
            s += __shfl_xor(s, 1);
            s += __shfl_xor(s, 2);
            s += __shfl_xor(s, 4);
            s += __shfl_xor(s, 8);
            float sc = 8.0f / fmaxf(sqrtf(s), 1e-4f);
            if (col == 0)
                vsA[(size_t)bh * NPIX + pw + pt * 16 + 4 * lg + r] = sc;
        }
    }
    #pragma unroll
    for (int ot = 0; ot < 4; ot++) {
        int d = ot * 16 + col;
        #pragma unroll
        for (int pt = 0; pt < 4; pt++) {
            uint2 uu;
            uu.x = pkbf(acc[pt][ot][0], acc[pt][ot][1]);
            uu.y = pkbf(acc[pt][ot][2], acc[pt][ot][3]);
            *(uint2*)(Vb + ((size_t)bh * DIMH + d) * NPIX + pw + pt * 16 + 4 * lg) = uu;
        }
    }
}

// ---------------------------------------------------------------------------
// Kernel 6: MFMA flash attention (round-2 body; epilogue -> bf16 token-major)
// ---------------------------------------------------------------------------
__global__ __launch_bounds__(256) void attn_mfma_kernel(
    const __hip_bfloat16* __restrict__ Qb,
    const __hip_bfloat16* __restrict__ Kb,
    const __hip_bfloat16* __restrict__ Vb,
    const float* __restrict__ qsA, const float* __restrict__ ksA,
    const float* __restrict__ vsA,
    const __hip_bfloat16* __restrict__ mk, const __hip_bfloat16* __restrict__ mv,
    const float* __restrict__ msk, const float* __restrict__ msv,
    ushort* __restrict__ attT)
{
    int b = blockIdx.z, h = blockIdx.y, bh = b * HEADS + h;
    int wave = threadIdx.x >> 6, lane = threadIdx.x & 63;
    int col = lane & 15, lg = lane >> 4;
    int q0 = blockIdx.x * 128 + wave * 32;

    __shared__ float sKs[NPIX], sVs[NPIX];
    {
        int t4 = threadIdx.x * 4;
        *(float4*)&sKs[t4] = *(const float4*)&ksA[(size_t)bh * NPIX + t4];
        *(float4*)&sVs[t4] = *(const float4*)&vsA[(size_t)bh * NPIX + t4];
    }
    __syncthreads();

    const __hip_bfloat16* Qbase = Qb + ((size_t)bh * NPIX + q0) * DIMH;
    const __hip_bfloat16* Kbase = Kb + (size_t)bh * NPIX * DIMH;
    const __hip_bfloat16* Vbase = Vb + (size_t)bh * DIMH * NPIX;

    v8s qf[2][2];
    float myqs[2];
    #pragma unroll
    for (int qt = 0; qt < 2; qt++) {
        #pragma unroll
        for (int dh = 0; dh < 2; dh++)
            qf[qt][dh] = *(const v8s*)(Qbase + (qt * 16 + col) * DIMH + dh * 32 + 8 * lg);
        myqs[qt] = qsA[(size_t)bh * NPIX + q0 + qt * 16 + col];
    }

    v4f o_[2][4];
    #pragma unroll
    for (int qt = 0; qt < 2; qt++)
        #pragma unroll
        for (int dt = 0; dt < 4; dt++) o_[qt][dt] = (v4f){0.f, 0.f, 0.f, 0.f};
    float m_[2] = {-1e30f, -1e30f};
    float l_[2] = {0.f, 0.f};

    int srcA = ((lg & 1) << 5) + col;
    int srcB = srcA + 16;
    bool hig = (lg >= 2);

    // ---- mem-kv tile ----
    {
        const __hip_bfloat16* mkh = mk + (size_t)h * 16 * DIMH;
        v8s kf0 = *(const v8s*)(mkh + col * DIMH + 8 * lg);
        v8s kf1 = *(const v8s*)(mkh + col * DIMH + 32 + 8 * lg);
        v8s vf[4];
        #pragma unroll
        for (int dt = 0; dt < 4; dt++)
            vf[dt] = *(const v8s*)(mv + ((size_t)h * DIMH + dt * 16 + col) * 32 + 8 * lg);
        float4 ksm = *(const float4*)&msk[h * 16 + 4 * lg];
        float4 vsm = *(const float4*)&msv[h * 32 + 4 * lg];
        float ksr[4] = {ksm.x, ksm.y, ksm.z, ksm.w};
        float vsr[4] = {vsm.x, vsm.y, vsm.z, vsm.w};

        #pragma unroll
        for (int qt = 0; qt < 2; qt++) {
            v4f c0 = (v4f){0.f, 0.f, 0.f, 0.f};
            c0 = MFMA16(kf0, qf[qt][0], c0);
            c0 = MFMA16(kf1, qf[qt][1], c0);
            float s0[4], p0[4];
            #pragma unroll
            for (int r = 0; r < 4; r++)
                s0[r] = (lg == 0) ? c0[r] * myqs[qt] * ksr[r] : -1e30f;
            float tm = fmaxf(fmaxf(s0[0], s0[1]), fmaxf(s0[2], s0[3]));
            tm = fmaxf(tm, __shfl_xor(tm, 16));
            tm = fmaxf(tm, __shfl_xor(tm, 32));
            float mnew = fmaxf(m_[qt], tm);
            float fs = __expf(m_[qt] - mnew);
            m_[qt] = mnew;
            float sum = 0.f;
            #pragma unroll
            for (int r = 0; r < 4; r++) { p0[r] = __expf(s0[r] - mnew); sum += p0[r]; }
            sum += __shfl_xor(sum, 16);
            sum += __shfl_xor(sum, 32);
            l_[qt] = l_[qt] * fs + sum;
            #pragma unroll
            for (int dt = 0; dt < 4; dt++) o_[qt][dt] *= fs;

            unsigned A0 = pkbf(p0[0] * vsr[0], p0[1] * vsr[1]);
            unsigned A1 = pkbf(p0[2] * vsr[2], p0[3] * vsr[3]);
            int a0 = __shfl((int)A0, srcA), a1 = __shfl((int)A1, srcA);
            int a2 = __shfl((int)A0, srcB), a3 = __shfl((int)A1, srcB);
            v4i w;
            w.x = hig ? 0 : a0; w.y = hig ? 0 : a1;
            w.z = hig ? 0 : a2; w.w = hig ? 0 : a3;
            v8s pf = __builtin_bit_cast(v8s, w);
            #pragma unroll
            for (int dt = 0; dt < 4; dt++)
                o_[qt][dt] = MFMA16(vf[dt], pf, o_[qt][dt]);
        }
    }

    // ---- main loop ----
    for (int k0 = 0; k0 < NPIX; k0 += 32) {
        const __hip_bfloat16* Kr = Kbase + (size_t)k0 * DIMH;
        v8s kf[4];
        kf[0] = *(const v8s*)(Kr + col * DIMH + 8 * lg);
        kf[1] = *(const v8s*)(Kr + col * DIMH + 32 + 8 * lg);
        kf[2] = *(const v8s*)(Kr + (16 + col) * DIMH + 8 * lg);
        kf[3] = *(const v8s*)(Kr + (16 + col) * DIMH + 32 + 8 * lg);
        v8s vf[4];
        #pragma unroll
        for (int dt = 0; dt < 4; dt++)
            vf[dt] = *(const v8s*)(Vbase + (size_t)(dt * 16 + col) * NPIX + k0 + 8 * lg);
        float4 ks0 = *(const float4*)&sKs[k0 + 4 * lg];
        float4 ks1 = *(const float4*)&sKs[k0 + 16 + 4 * lg];
        float4 vs0 = *(const float4*)&sVs[k0 + 4 * lg];
        float4 vs1 = *(const float4*)&sVs[k0 + 16 + 4 * lg];
        float ksr0[4] = {ks0.x, ks0.y, ks0.z, ks0.w};
        float ksr1[4] = {ks1.x, ks1.y, ks1.z, ks1.w};
        float vsr0[4] = {vs0.x, vs0.y, vs0.z, vs0.w};
        float vsr1[4] = {vs1.x, vs1.y, vs1.z, vs1.w};

        #pragma unroll
        for (int qt = 0; qt < 2; qt++) {
            v4f c0 = (v4f){0.f, 0.f, 0.f, 0.f};
            v4f c1 = (v4f){0.f, 0.f, 0.f, 0.f};
            c0 = MFMA16(kf[0], qf[qt][0], c0);
            c0 = MFMA16(kf[1], qf[qt][1], c0);
            c1 = MFMA16(kf[2], qf[qt][0], c1);
            c1 = MFMA16(kf[3], qf[qt][1], c1);

            float s0[4], s1[4], p0[4], p1[4];
            #pragma unroll
            for (int r = 0; r < 4; r++) {
                s0[r] = c0[r] * myqs[qt] * ksr0[r];
                s1[r] = c1[r] * myqs[qt] * ksr1[r];
            }
            float tm = fmaxf(fmaxf(fmaxf(s0[0], s0[1]), fmaxf(s0[2], s0[3])),
                             fmaxf(fmaxf(s1[0], s1[1]), fmaxf(s1[2], s1[3])));
            tm = fmaxf(tm, __shfl_xor(tm, 16));
            tm = fmaxf(tm, __shfl_xor(tm, 32));
            float mnew = fmaxf(m_[qt], tm);
            float fs = __expf(m_[qt] - mnew);
            m_[qt] = mnew;
            float sum = 0.f;
            #pragma unroll
            for (int r = 0; r < 4; r++) {
                p0[r] = __expf(s0[r] - mnew); sum += p0[r];
                p1[r] = __expf(s1[r] - mnew); sum += p1[r];
            }
            sum += __shfl_xor(sum, 16);
            sum += __shfl_xor(sum, 32);
            l_[qt] = l_[qt] * fs + sum;
            #pragma unroll
            for (int dt = 0; dt < 4; dt++) o_[qt][dt] *= fs;

            unsigned A0 = pkbf(p0[0] * vsr0[0], p0[1] * vsr0[1]);
            unsigned A1 = pkbf(p0[2] * vsr0[2], p0[3] * vsr0[3]);
            unsigned B0 = pkbf(p1[0] * vsr1[0], p1[1] * vsr1[1]);
            unsigned B1 = pkbf(p1[2] * vsr1[2], p1[3] * vsr1[3]);
            int a0 = __shfl((int)A0, srcA), a1 = __shfl((int)A1, srcA);
            int a2 = __shfl((int)A0, srcB), a3 = __shfl((int)A1, srcB);
            int b0 = __shfl((int)B0, srcA), b1 = __shfl((int)B1, srcA);
            int b2 = __shfl((int)B0, srcB), b3 = __shfl((int)B1, srcB);
            v4i w;
            w.x = hig ? b0 : a0; w.y = hig ? b1 : a1;
            w.z = hig ? b2 : a2; w.w = hig ? b3 : a3;
            v8s pf = __builtin_bit_cast(v8s, w);
            #pragma unroll
            for (int dt = 0; dt < 4; dt++)
                o_[qt][dt] = MFMA16(vf[dt], pf, o_[qt][dt]);
        }
    }

    // ---- epilogue: bf16 token-major attT[b][q][h*64+d] ----
    #pragma unroll
    for (int qt = 0; qt < 2; qt++) {
        float invl = 1.0f / l_[qt];
        ushort* at = attT + ((size_t)(b * NPIX + q0 + qt * 16 + col)) * HIDDEN + h * DIMH;
        #pragma unroll
        for (int dt = 0; dt < 4; dt++) {
            uint2 uu;
            uu.x = pkbf(o_[qt][dt][0] * invl, o_[qt][dt][1] * invl);
            uu.y = pkbf(o_[qt][dt][2] * invl, o_[qt][dt][3] * invl);
            *(uint2*)(at + dt * 16 + 4 * lg) = uu;
        }
    }
}

// ---------------------------------------------------------------------------
// Kernel 7: out-proj GEMM, swapped orientation D[p][o] = attT·Wo^T,
// fused MPAdd epilogue with float4 stores.
// ---------------------------------------------------------------------------
__global__ __launch_bounds__(256) void gemm_out_mfma(
    const ushort* __restrict__ Wo,   // [512][512] (= wn rows 1536..2048)
    const ushort* __restrict__ attT, // [B][1024][512]
    const float* __restrict__ x, float* __restrict__ out)
{
    int b = blockIdx.z;
    int o0 = blockIdx.y * 128;
    int p0 = blockIdx.x * 128;
    int wave = threadIdx.x >> 6, lane = threadIdx.x & 63;
    int wy = wave >> 1, wx = wave & 1;
    int col = lane & 15, lg = lane >> 4;
    int ow = o0 + wy * 64, pw = p0 + wx * 64;

    const ushort* Abase = attT + ((size_t)b * NPIX + pw + col) * HIDDEN + 8 * lg;
    const ushort* Bbase = Wo + (size_t)(ow + col) * HIDDEN + 8 * lg;

    v4f acc[4][4];   // [pt][ot]
    #pragma unroll
    for (int i = 0; i < 4; i++)
        #pragma unroll
        for (int j = 0; j < 4; j++) acc[i][j] = (v4f){0.f, 0.f, 0.f, 0.f};

    v8s a0[4], b0[4], a1[4], b1[4];
    #pragma unroll
    for (int i = 0; i < 4; i++) {
        a0[i] = *(const v8s*)(Abase + (size_t)i * 16 * HIDDEN);
        b0[i] = *(const v8s*)(Bbase + (size_t)i * 16 * HIDDEN);
    }
    #pragma unroll 1
    for (int c0 = 0; c0 < HIDDEN; c0 += 64) {
        #pragma unroll
        for (int i = 0; i < 4; i++) {
            a1[i] = *(const v8s*)(Abase + (size_t)i * 16 * HIDDEN + c0 + 32);
            b1[i] = *(const v8s*)(Bbase + (size_t)i * 16 * HIDDEN + c0 + 32);
        }
        #pragma unroll
        for (int pt = 0; pt < 4; pt++)
            #pragma unroll
            for (int ot = 0; ot < 4; ot++)
                acc[pt][ot] = MFMA16(a0[pt], b0[ot], acc[pt][ot]);
        if (c0 + 64 < HIDDEN) {
            #pragma unroll
            for (int i = 0; i < 4; i++) {
                a0[i] = *(const v8s*)(Abase + (size_t)i * 16 * HIDDEN + c0 + 64);
                b0[i] = *(const v8s*)(Bbase + (size_t)i * 16 * HIDDEN + c0 + 64);
            }
        }
        #pragma unroll
        for (int pt = 0; pt < 4; pt++)
            #pragma unroll
            for (int ot = 0; ot < 4; ot++)
                acc[pt][ot] = MFMA16(a1[pt], b1[ot], acc[pt][ot]);
    }

    const float INV_DEN = 1.3130643285972254f;
    #pragma unroll
    for (int pt = 0; pt < 4; pt++) {
        #pragma unroll
        for (int ot = 0; ot < 4; ot++) {
            size_t base = ((size_t)b * HIDDEN + ow + ot * 16 + col) * NPIX
                        + pw + pt * 16 + 4 * lg;
            float4 res = *(const float4*)&x[base];
            float4 y;
            y.x = (acc[pt][ot][0] * 0.7f + res.x * 0.3f) * INV_DEN;
            y.y = (acc[pt][ot][1] * 0.7f + res.y * 0.3f) * INV_DEN;
            y.z = (acc[pt][ot][2] * 0.7f + res.z * 0.3f) * INV_DEN;
            y.w = (acc[pt][ot][3] * 0.7f + res.w * 0.3f) * INV_DEN;
            *(float4*)&out[base] = y;
        }
    }
}

// ---------------------------------------------------------------------------
extern "C" void kernel_launch(void* const* d_in, const int* in_sizes, int n_in,
                              void* d_out, int out_size, void* d_ws, size_t ws_size,
                              hipStream_t stream)
{
    const float* x      = (const float*)d_in[0];
    const float* w_qkv  = (const float*)d_in[1];
    const float* w_out  = (const float*)d_in[2];
    const float* mem_kv = (const float*)d_in[3];
    float* out = (float*)d_out;

    char* ws = (char*)d_ws;
    ushort* wnB = (ushort*)ws; ws += (size_t)2048 * CIN * 2;
    ushort* Xt  = (ushort*)ws; ws += (size_t)BATCH * NPIX * CIN * 2;
    ushort* Qb  = (ushort*)ws; ws += (size_t)BATCH * HEADS * NPIX * DIMH * 2;
    ushort* Kb  = (ushort*)ws; ws += (size_t)BATCH * HEADS * NPIX * DIMH * 2;
    ushort* Vb  = (ushort*)ws; ws += (size_t)BATCH * HEADS * NPIX * DIMH * 2;
    ushort* attT = (ushort*)ws; ws += (size_t)BATCH * NPIX * HIDDEN * 2;
    float* qsA = (float*)ws;  ws += (size_t)BATCH * HEADS * NPIX * 4;
    float* ksA = (float*)ws;  ws += (size_t)BATCH * HEADS * NPIX * 4;
    float* vsA = (float*)ws;  ws += (size_t)BATCH * HEADS * NPIX * 4;
    float* msk = (float*)ws;  ws += 8 * 16 * 4;
    float* msv = (float*)ws;  ws += 8 * 32 * 4;
    __hip_bfloat16* mk = (__hip_bfloat16*)ws; ws += (size_t)8 * 16 * 64 * 2;
    __hip_bfloat16* mv = (__hip_bfloat16*)ws; ws += (size_t)8 * 64 * 32 * 2;

    wnorm_kernel<<<2048, 256, 0, stream>>>(w_qkv, w_out, wnB);
    xT_kernel<<<dim3(16, 8, BATCH), 256, 0, stream>>>(x, Xt);
    memkv_prep<<<8, 64, 0, stream>>>(mem_kv, mk, mv, msk, msv);

    gemm_qk_mfma<<<dim3(8, 8, BATCH), 256, 0, stream>>>(
        wnB, Xt, Qb, Kb, qsA, ksA);
    gemm_v_mfma<<<dim3(8, 4, BATCH), 256, 0, stream>>>(
        wnB + (size_t)1024 * CIN, Xt, Vb, vsA);

    attn_mfma_kernel<<<dim3(8, HEADS, BATCH), 256, 0, stream>>>(
        (const __hip_bfloat16*)Qb, (const __hip_bfloat16*)Kb,
        (const __hip_bfloat16*)Vb, qsA, ksA, vsA, mk, mv, msk, msv, attT);

    gemm_out_mfma<<<dim3(8, 4, BATCH), 256, 0, stream>>>(
        wnB + (size_t)OQKV * CIN, attT, x, out);
}